// Round 8
// baseline (219.263 us; speedup 1.0000x reference)
//
#include <hip/hip_runtime.h>

#define N_BATCH 4096
#define K_ACT   32
#define D_FEAT  49152
#define BASE    512

typedef unsigned short ushort_t;
typedef __attribute__((ext_vector_type(8))) unsigned short ushort8;

__device__ __forceinline__ ushort_t f2bf(float f) {
    unsigned u = __builtin_bit_cast(unsigned, f);
    u += 0x7FFFu + ((u >> 16) & 1u);          // round-to-nearest-even
    return (ushort_t)(u >> 16);
}

// Kernel 1: Rb[d, r] = bf16( W_aff[r, d] + w0[f0[d], r] + w1[f1[d], r] )
// 128(r) x 128(d) tile, 64KB LDS, 2 blocks/CU. Reads: 128 rows x 512B bursts.
// Writes: per d-row 4x64B (one 256B burst per block, full rows across the
// 4 r-tile blocks). LDS swizzle S(rl) = (rl&31)^(rl>>5) on the float4-group:
// verified conflict-free for phase-1 b128 writes and phase-2 b32 reads.
__global__ __launch_bounds__(512) void build_R_kernel(
    const float* __restrict__ W_aff,
    const float* __restrict__ w0,
    const float* __restrict__ w1,
    const int* __restrict__ f0,
    const int* __restrict__ f1,
    ushort_t* __restrict__ Rb)
{
    __shared__ float tile[128 * 128];     // 64 KB
    const int r0 = blockIdx.x * 128;      // fast dim: 4 r-tiles
    const int d0 = blockIdx.y * 128;      // slow dim: 384 d-tiles
    const int t  = threadIdx.x;

    // Phase 1: read W_aff rows (contiguous in d; 512B per row) as float4.
    {
        const int x   = t & 31;           // float4 group within row (0..31)
        const int rl0 = t >> 5;           // 0..15
        const float4* W4 = (const float4*)W_aff;
#pragma unroll
        for (int i = 0; i < 8; ++i) {
            const int rl = rl0 + 16 * i;  // 0..127
            float4 w = W4[(size_t)(r0 + rl) * (D_FEAT / 4) + (d0 >> 2) + x];
            const int S = (rl & 31) ^ (rl >> 5);
            ((float4*)tile)[rl * 32 + (x ^ S)] = w;
        }
    }
    __syncthreads();

    // Phase 2: thread = (dl, seg): dl in 0..127, seg in 0..3 covers r-range
    // [seg*32, seg*32+32). Gathers a 32-long r-column for its d, adds the
    // block tables, converts to bf16, stores 64B contiguous.
    const int dl  = t & 127;
    const int seg = t >> 7;               // 0..3
    const int d   = d0 + dl;
    const int g   = dl >> 2;
    const int e   = dl & 3;

    float a[32];
#pragma unroll
    for (int j = 0; j < 32; ++j) {
        const int rl = seg * 32 + j;
        const int S  = j ^ seg;           // (rl&31) ^ (rl>>5)
        a[j] = tile[rl * 128 + ((g ^ S) << 2) + e];
    }

    const int i0 = f0[d];
    const int i1 = f1[d];
    const float4* w0v = (const float4*)w0;
    const float4* w1v = (const float4*)w1;
    const size_t b0base = (size_t)i0 * (BASE / 4) + (r0 >> 2) + seg * 8;
    const size_t b1base = (size_t)i1 * (BASE / 4) + (r0 >> 2) + seg * 8;
#pragma unroll
    for (int q = 0; q < 8; ++q) {
        const float4 b0 = w0v[b0base + q];
        const float4 b1 = w1v[b1base + q];
        a[4 * q + 0] += b0.x + b1.x;
        a[4 * q + 1] += b0.y + b1.y;
        a[4 * q + 2] += b0.z + b1.z;
        a[4 * q + 3] += b0.w + b1.w;
    }

    ushort_t* dst = &Rb[(size_t)d * BASE + r0 + seg * 32];
#pragma unroll
    for (int q = 0; q < 4; ++q) {
        ushort8 o;
#pragma unroll
        for (int j = 0; j < 8; ++j) o[j] = f2bf(a[8 * q + j]);
        *(ushort8*)&dst[8 * q] = o;
    }
}

// Kernel 2: out[n, :] = b_aff + sum_k v[n,k] * Rb[idx[n,k], :]
// One n per 64-lane wave; lane covers 8 outputs (ushort8 = 16B load => each
// k-iteration reads the 1KB bf16 R row fully coalesced).
__global__ __launch_bounds__(256) void gather_out_kernel(
    const ushort_t* __restrict__ Rb,
    const float* __restrict__ x_val,
    const int*   __restrict__ x_idx,
    const float* __restrict__ b_aff,
    float* __restrict__ out)
{
    const int lane = threadIdx.x & 63;
    const int wv   = threadIdx.x >> 6;     // 0..3
    const int n    = blockIdx.x * 4 + wv;

    float acc[8];
    {
        const float4 bb0 = ((const float4*)b_aff)[2 * lane];
        const float4 bb1 = ((const float4*)b_aff)[2 * lane + 1];
        acc[0] = bb0.x; acc[1] = bb0.y; acc[2] = bb0.z; acc[3] = bb0.w;
        acc[4] = bb1.x; acc[5] = bb1.y; acc[6] = bb1.z; acc[7] = bb1.w;
    }

    const int*   idxp = x_idx + (size_t)n * K_ACT;
    const float* valp = x_val + (size_t)n * K_ACT;

#pragma unroll
    for (int k = 0; k < K_ACT; ++k) {
        const int   idx = idxp[k];
        const float v   = valp[k];
        const ushort8 w = *(const ushort8*)&Rb[(size_t)idx * BASE + 8 * lane];
#pragma unroll
        for (int j = 0; j < 8; ++j) {
            const float wf = __builtin_bit_cast(float, (unsigned)w[j] << 16);
            acc[j] = fmaf(v, wf, acc[j]);
        }
    }

    float4 o0, o1;
    o0.x = acc[0]; o0.y = acc[1]; o0.z = acc[2]; o0.w = acc[3];
    o1.x = acc[4]; o1.y = acc[5]; o1.z = acc[6]; o1.w = acc[7];
    ((float4*)out)[(size_t)n * (BASE / 4) + 2 * lane]     = o0;
    ((float4*)out)[(size_t)n * (BASE / 4) + 2 * lane + 1] = o1;
}

// Fallback (only if d_ws can't hold the 48MB bf16 R table): direct gather.
__global__ __launch_bounds__(512) void direct_kernel(
    const float* __restrict__ x_val,
    const float* __restrict__ W_aff,
    const float* __restrict__ b_aff,
    const float* __restrict__ w0,
    const float* __restrict__ w1,
    const int*   __restrict__ x_idx,
    const int*   __restrict__ f0,
    const int*   __restrict__ f1,
    float* __restrict__ out)
{
    const int n = blockIdx.x;
    const int r = threadIdx.x;  // 0..511
    float acc = b_aff[r];
    for (int k = 0; k < K_ACT; ++k) {
        const int   idx = x_idx[(size_t)n * K_ACT + k];
        const float v   = x_val[(size_t)n * K_ACT + k];
        float w = W_aff[(size_t)r * D_FEAT + idx];
        w += w0[(size_t)f0[idx] * BASE + r];
        w += w1[(size_t)f1[idx] * BASE + r];
        acc += v * w;
    }
    out[(size_t)n * BASE + r] = acc;
}

extern "C" void kernel_launch(void* const* d_in, const int* in_sizes, int n_in,
                              void* d_out, int out_size, void* d_ws, size_t ws_size,
                              hipStream_t stream) {
    const float* x_val = (const float*)d_in[0];
    const float* W_aff = (const float*)d_in[1];
    const float* b_aff = (const float*)d_in[2];
    const float* w0    = (const float*)d_in[3];
    const float* w1    = (const float*)d_in[4];
    const int*   x_idx = (const int*)d_in[5];
    const int*   f0    = (const int*)d_in[6];
    const int*   f1    = (const int*)d_in[7];
    float* out = (float*)d_out;

    const size_t needR = (size_t)D_FEAT * BASE * sizeof(ushort_t);  // ~48 MB
    if (ws_size >= needR) {
        ushort_t* Rb = (ushort_t*)d_ws;
        dim3 grid(BASE / 128, D_FEAT / 128);   // 4 (fast, r) x 384 (slow, d)
        build_R_kernel<<<grid, 512, 0, stream>>>(W_aff, w0, w1, f0, f1, Rb);
        gather_out_kernel<<<N_BATCH / 4, 256, 0, stream>>>(Rb, x_val, x_idx, b_aff, out);
    } else {
        direct_kernel<<<N_BATCH, BASE, 0, stream>>>(x_val, W_aff, b_aff, w0, w1,
                                                    x_idx, f0, f1, out);
    }
}

// Round 9
// 217.561 us; speedup vs baseline: 1.0078x; 1.0078x over previous
//
#include <hip/hip_runtime.h>

#define N_BATCH 4096
#define K_ACT   32
#define D_FEAT  49152
#define BASE    512

typedef unsigned short ushort_t;
typedef __attribute__((ext_vector_type(8))) unsigned short ushort8;

__device__ __forceinline__ ushort_t f2bf(float f) {
    unsigned u = __builtin_bit_cast(unsigned, f);
    u += 0x7FFFu + ((u >> 16) & 1u);          // round-to-nearest-even
    return (ushort_t)(u >> 16);
}

// Kernel 1: Rb[d, r] = bf16( W_aff[r, d] + w0[f0[d], r] + w1[f1[d], r] )
// 128(r) x 128(d) tile, 64KB LDS, 1024 threads -> 2 blocks/CU x 16 waves
// = 32 waves/CU (100% occupancy). Reads: 512B bursts per W_aff row.
// Writes: 8 segs x 32B per d-row = 256B contiguous per block; full 1KB rows
// assembled across the 4 r-tile blocks (r is the fast grid dim).
// LDS swizzle S(rl) = (rl&31)^(rl>>5) on the float4-group: phase-1 b128
// writes conflict-free; phase-2 b32 column reads 2-way (free).
__global__ __launch_bounds__(1024) void build_R_kernel(
    const float* __restrict__ W_aff,
    const float* __restrict__ w0,
    const float* __restrict__ w1,
    const int* __restrict__ f0,
    const int* __restrict__ f1,
    ushort_t* __restrict__ Rb)
{
    __shared__ float tile[128 * 128];     // 64 KB
    const int r0 = blockIdx.x * 128;      // fast dim: 4 r-tiles
    const int d0 = blockIdx.y * 128;      // slow dim: 384 d-tiles
    const int t  = threadIdx.x;

    // Phase 1: read W_aff rows (contiguous in d; 512B per row) as float4.
    {
        const int x   = t & 31;           // float4 group within row (0..31)
        const int rl0 = t >> 5;           // 0..31
        const float4* W4 = (const float4*)W_aff;
#pragma unroll
        for (int i = 0; i < 4; ++i) {
            const int rl = rl0 + 32 * i;  // 0..127
            float4 w = W4[(size_t)(r0 + rl) * (D_FEAT / 4) + (d0 >> 2) + x];
            const int S = (rl & 31) ^ (rl >> 5);
            ((float4*)tile)[rl * 32 + (x ^ S)] = w;
        }
    }
    __syncthreads();

    // Phase 2: thread = (dl, seg): dl in 0..127, seg in 0..7 covers r-range
    // [seg*16, seg*16+16). Gather 16-long r-column, add block tables,
    // convert to bf16, store 32B contiguous.
    const int dl  = t & 127;
    const int seg = t >> 7;               // 0..7
    const int d   = d0 + dl;
    const int g   = dl >> 2;
    const int e   = dl & 3;

    float a[16];
#pragma unroll
    for (int j = 0; j < 16; ++j) {
        const int rl = seg * 16 + j;
        const int S  = (rl & 31) ^ (rl >> 5);
        a[j] = tile[rl * 128 + ((g ^ S) << 2) + e];
    }

    const int i0 = f0[d];
    const int i1 = f1[d];
    const float4* w0v = (const float4*)w0;
    const float4* w1v = (const float4*)w1;
    const size_t b0base = (size_t)i0 * (BASE / 4) + (r0 >> 2) + seg * 4;
    const size_t b1base = (size_t)i1 * (BASE / 4) + (r0 >> 2) + seg * 4;
#pragma unroll
    for (int q = 0; q < 4; ++q) {
        const float4 b0 = w0v[b0base + q];
        const float4 b1 = w1v[b1base + q];
        a[4 * q + 0] += b0.x + b1.x;
        a[4 * q + 1] += b0.y + b1.y;
        a[4 * q + 2] += b0.z + b1.z;
        a[4 * q + 3] += b0.w + b1.w;
    }

    ushort_t* dst = &Rb[(size_t)d * BASE + r0 + seg * 16];
#pragma unroll
    for (int q = 0; q < 2; ++q) {
        ushort8 o;
#pragma unroll
        for (int j = 0; j < 8; ++j) o[j] = f2bf(a[8 * q + j]);
        *(ushort8*)&dst[8 * q] = o;
    }
}

// Kernel 2: out[n, :] = b_aff + sum_k v[n,k] * Rb[idx[n,k], :]
// One n per 64-lane wave; lane covers 8 outputs (ushort8 = 16B load => each
// k-iteration reads the 1KB bf16 R row fully coalesced).
__global__ __launch_bounds__(256) void gather_out_kernel(
    const ushort_t* __restrict__ Rb,
    const float* __restrict__ x_val,
    const int*   __restrict__ x_idx,
    const float* __restrict__ b_aff,
    float* __restrict__ out)
{
    const int lane = threadIdx.x & 63;
    const int wv   = threadIdx.x >> 6;     // 0..3
    const int n    = blockIdx.x * 4 + wv;

    float acc[8];
    {
        const float4 bb0 = ((const float4*)b_aff)[2 * lane];
        const float4 bb1 = ((const float4*)b_aff)[2 * lane + 1];
        acc[0] = bb0.x; acc[1] = bb0.y; acc[2] = bb0.z; acc[3] = bb0.w;
        acc[4] = bb1.x; acc[5] = bb1.y; acc[6] = bb1.z; acc[7] = bb1.w;
    }

    const int*   idxp = x_idx + (size_t)n * K_ACT;
    const float* valp = x_val + (size_t)n * K_ACT;

#pragma unroll
    for (int k = 0; k < K_ACT; ++k) {
        const int   idx = idxp[k];
        const float v   = valp[k];
        const ushort8 w = *(const ushort8*)&Rb[(size_t)idx * BASE + 8 * lane];
#pragma unroll
        for (int j = 0; j < 8; ++j) {
            const float wf = __builtin_bit_cast(float, (unsigned)w[j] << 16);
            acc[j] = fmaf(v, wf, acc[j]);
        }
    }

    float4 o0, o1;
    o0.x = acc[0]; o0.y = acc[1]; o0.z = acc[2]; o0.w = acc[3];
    o1.x = acc[4]; o1.y = acc[5]; o1.z = acc[6]; o1.w = acc[7];
    ((float4*)out)[(size_t)n * (BASE / 4) + 2 * lane]     = o0;
    ((float4*)out)[(size_t)n * (BASE / 4) + 2 * lane + 1] = o1;
}

// Fallback (only if d_ws can't hold the 48MB bf16 R table): direct gather.
__global__ __launch_bounds__(512) void direct_kernel(
    const float* __restrict__ x_val,
    const float* __restrict__ W_aff,
    const float* __restrict__ b_aff,
    const float* __restrict__ w0,
    const float* __restrict__ w1,
    const int*   __restrict__ x_idx,
    const int*   __restrict__ f0,
    const int*   __restrict__ f1,
    float* __restrict__ out)
{
    const int n = blockIdx.x;
    const int r = threadIdx.x;  // 0..511
    float acc = b_aff[r];
    for (int k = 0; k < K_ACT; ++k) {
        const int   idx = x_idx[(size_t)n * K_ACT + k];
        const float v   = x_val[(size_t)n * K_ACT + k];
        float w = W_aff[(size_t)r * D_FEAT + idx];
        w += w0[(size_t)f0[idx] * BASE + r];
        w += w1[(size_t)f1[idx] * BASE + r];
        acc += v * w;
    }
    out[(size_t)n * BASE + r] = acc;
}

extern "C" void kernel_launch(void* const* d_in, const int* in_sizes, int n_in,
                              void* d_out, int out_size, void* d_ws, size_t ws_size,
                              hipStream_t stream) {
    const float* x_val = (const float*)d_in[0];
    const float* W_aff = (const float*)d_in[1];
    const float* b_aff = (const float*)d_in[2];
    const float* w0    = (const float*)d_in[3];
    const float* w1    = (const float*)d_in[4];
    const int*   x_idx = (const int*)d_in[5];
    const int*   f0    = (const int*)d_in[6];
    const int*   f1    = (const int*)d_in[7];
    float* out = (float*)d_out;

    const size_t needR = (size_t)D_FEAT * BASE * sizeof(ushort_t);  // ~48 MB
    if (ws_size >= needR) {
        ushort_t* Rb = (ushort_t*)d_ws;
        dim3 grid(BASE / 128, D_FEAT / 128);   // 4 (fast, r) x 384 (slow, d)
        build_R_kernel<<<grid, 1024, 0, stream>>>(W_aff, w0, w1, f0, f1, Rb);
        gather_out_kernel<<<N_BATCH / 4, 256, 0, stream>>>(Rb, x_val, x_idx, b_aff, out);
    } else {
        direct_kernel<<<N_BATCH, BASE, 0, stream>>>(x_val, W_aff, b_aff, w0, w1,
                                                    x_idx, f0, f1, out);
    }
}

// Round 14
// 199.101 us; speedup vs baseline: 1.1013x; 1.0927x over previous
//
#include <hip/hip_runtime.h>

#define N_BATCH 4096
#define K_ACT   32
#define D_FEAT  49152
#define BASE    512
#define PANEL_R 128                       // r-columns per panel
#define PANEL_ELEMS ((size_t)D_FEAT * PANEL_R)   // ushorts per panel

typedef unsigned short ushort_t;
typedef __attribute__((ext_vector_type(8))) unsigned short ushort8;

__device__ __forceinline__ ushort_t f2bf(float f) {
    unsigned u = __builtin_bit_cast(unsigned, f);
    u += 0x7FFFu + ((u >> 16) & 1u);          // round-to-nearest-even
    return (ushort_t)(u >> 16);
}

// Kernel 1: R stored as 4 panels: Rp[p][d][128] bf16, p = r-tile (r = p*128+..).
// Rp[p][d][rr] = bf16( W_aff[p*128+rr, d] + w0[f0[d], p*128+rr] + w1[...] ).
// 128(r) x 128(d) tile, 64KB LDS, 1024 threads. Phase-1 reads: 512B bursts.
// Phase-2 writes: each store instruction = 1KB CONTIGUOUS (4 d-rows x 256B);
// whole block writes one contiguous 32KB panel region.
__global__ __launch_bounds__(1024) void build_R_kernel(
    const float* __restrict__ W_aff,
    const float* __restrict__ w0,
    const float* __restrict__ w1,
    const int* __restrict__ f0,
    const int* __restrict__ f1,
    ushort_t* __restrict__ Rb)
{
    __shared__ float tile[128 * 128];     // 64 KB
    const int p  = blockIdx.x;            // panel / r-tile (fast dim, 4)
    const int r0 = p * 128;
    const int d0 = blockIdx.y * 128;      // slow dim: 384 d-tiles
    const int t  = threadIdx.x;

    // Phase 1: read W_aff rows (contiguous in d; 512B per row) as float4.
    {
        const int x   = t & 31;           // float4 group within row (0..31)
        const int rl0 = t >> 5;           // 0..31
        const float4* W4 = (const float4*)W_aff;
#pragma unroll
        for (int i = 0; i < 4; ++i) {
            const int rl = rl0 + 32 * i;  // 0..127
            float4 w = W4[(size_t)(r0 + rl) * (D_FEAT / 4) + (d0 >> 2) + x];
            const int S = (rl & 31) ^ (rl >> 5);
            ((float4*)tile)[rl * 32 + (x ^ S)] = w;
        }
    }
    __syncthreads();

    // Phase 2: wave w, lane l. Store s in {0,1}: d-row dl = w*8 + s*4 + (l>>4),
    // 16B chunk (l&15) -> per store instruction 64 lanes cover 4 d-rows x 256B
    // = 1KB contiguous. Block total: 128 rows x 256B = 32KB contiguous.
    const int w_  = t >> 6;               // 0..15
    const int l   = t & 63;
    const int lg  = l >> 4;               // 0..3
    const int lr  = l & 15;               // 0..15
    const float4* w0v = (const float4*)w0;
    const float4* w1v = (const float4*)w1;
    ushort_t* panel = Rb + (size_t)p * PANEL_ELEMS;

#pragma unroll
    for (int s = 0; s < 2; ++s) {
        const int dl = w_ * 8 + s * 4 + lg;   // 0..127
        const int d  = d0 + dl;
        const int g  = dl >> 2;
        const int e  = dl & 3;

        float a[8];
#pragma unroll
        for (int j = 0; j < 8; ++j) {
            const int rl = lr * 8 + j;
            const int S  = (rl & 31) ^ (rl >> 5);
            a[j] = tile[rl * 128 + ((g ^ S) << 2) + e];
        }

        const int i0 = f0[d];
        const int i1 = f1[d];
        const size_t bb = (size_t)(r0 >> 2) + lr * 2;
        const float4 b0 = w0v[(size_t)i0 * (BASE / 4) + bb];
        const float4 b1 = w0v[(size_t)i0 * (BASE / 4) + bb + 1];
        const float4 c0 = w1v[(size_t)i1 * (BASE / 4) + bb];
        const float4 c1 = w1v[(size_t)i1 * (BASE / 4) + bb + 1];
        a[0] += b0.x + c0.x;  a[1] += b0.y + c0.y;
        a[2] += b0.z + c0.z;  a[3] += b0.w + c0.w;
        a[4] += b1.x + c1.x;  a[5] += b1.y + c1.y;
        a[6] += b1.z + c1.z;  a[7] += b1.w + c1.w;

        ushort8 o;
#pragma unroll
        for (int j = 0; j < 8; ++j) o[j] = f2bf(a[j]);
        *(ushort8*)&panel[(size_t)d * PANEL_R + lr * 8] = o;
    }
}

// Kernel 2: out[n, :] = b_aff + sum_k v[n,k] * R[idx[n,k], :]
// One n per 64-lane wave. Lane handles r = (lane>>4)*128 + (lane&15)*8 .. +8:
// reads 16B from panel lane>>4. Per k: 4 x 256B contiguous panel reads.
__global__ __launch_bounds__(256) void gather_out_kernel(
    const ushort_t* __restrict__ Rb,
    const float* __restrict__ x_val,
    const int*   __restrict__ x_idx,
    const float* __restrict__ b_aff,
    float* __restrict__ out)
{
    const int lane = threadIdx.x & 63;
    const int wv   = threadIdx.x >> 6;     // 0..3
    const int n    = blockIdx.x * 4 + wv;
    const int p    = lane >> 4;            // panel
    const int lr   = lane & 15;            // 16B chunk within panel row

    const ushort_t* prow = Rb + (size_t)p * PANEL_ELEMS + lr * 8;
    const int fo = p * 32 + lr * 2;        // float4 index of this lane's 8 outs

    float acc[8];
    {
        const float4 bb0 = ((const float4*)b_aff)[fo];
        const float4 bb1 = ((const float4*)b_aff)[fo + 1];
        acc[0] = bb0.x; acc[1] = bb0.y; acc[2] = bb0.z; acc[3] = bb0.w;
        acc[4] = bb1.x; acc[5] = bb1.y; acc[6] = bb1.z; acc[7] = bb1.w;
    }

    const int*   idxp = x_idx + (size_t)n * K_ACT;
    const float* valp = x_val + (size_t)n * K_ACT;

#pragma unroll
    for (int k = 0; k < K_ACT; ++k) {
        const int   idx = idxp[k];
        const float v   = valp[k];
        const ushort8 w = *(const ushort8*)&prow[(size_t)idx * PANEL_R];
#pragma unroll
        for (int j = 0; j < 8; ++j) {
            const float wf = __builtin_bit_cast(float, (unsigned)w[j] << 16);
            acc[j] = fmaf(v, wf, acc[j]);
        }
    }

    float4 o0, o1;
    o0.x = acc[0]; o0.y = acc[1]; o0.z = acc[2]; o0.w = acc[3];
    o1.x = acc[4]; o1.y = acc[5]; o1.z = acc[6]; o1.w = acc[7];
    ((float4*)out)[(size_t)n * (BASE / 4) + fo]     = o0;
    ((float4*)out)[(size_t)n * (BASE / 4) + fo + 1] = o1;
}

// Fallback (only if d_ws can't hold the 48MB bf16 R table): direct gather.
__global__ __launch_bounds__(512) void direct_kernel(
    const float* __restrict__ x_val,
    const float* __restrict__ W_aff,
    const float* __restrict__ b_aff,
    const float* __restrict__ w0,
    const float* __restrict__ w1,
    const int*   __restrict__ x_idx,
    const int*   __restrict__ f0,
    const int*   __restrict__ f1,
    float* __restrict__ out)
{
    const int n = blockIdx.x;
    const int r = threadIdx.x;  // 0..511
    float acc = b_aff[r];
    for (int k = 0; k < K_ACT; ++k) {
        const int   idx = x_idx[(size_t)n * K_ACT + k];
        const float v   = x_val[(size_t)n * K_ACT + k];
        float w = W_aff[(size_t)r * D_FEAT + idx];
        w += w0[(size_t)f0[idx] * BASE + r];
        w += w1[(size_t)f1[idx] * BASE + r];
        acc += v * w;
    }
    out[(size_t)n * BASE + r] = acc;
}

extern "C" void kernel_launch(void* const* d_in, const int* in_sizes, int n_in,
                              void* d_out, int out_size, void* d_ws, size_t ws_size,
                              hipStream_t stream) {
    const float* x_val = (const float*)d_in[0];
    const float* W_aff = (const float*)d_in[1];
    const float* b_aff = (const float*)d_in[2];
    const float* w0    = (const float*)d_in[3];
    const float* w1    = (const float*)d_in[4];
    const int*   x_idx = (const int*)d_in[5];
    const int*   f0    = (const int*)d_in[6];
    const int*   f1    = (const int*)d_in[7];
    float* out = (float*)d_out;

    const size_t needR = (size_t)D_FEAT * BASE * sizeof(ushort_t);  // ~48 MB
    if (ws_size >= needR) {
        ushort_t* Rb = (ushort_t*)d_ws;
        dim3 grid(BASE / 128, D_FEAT / 128);   // 4 (fast, panel) x 384 (slow, d)
        build_R_kernel<<<grid, 1024, 0, stream>>>(W_aff, w0, w1, f0, f1, Rb);
        gather_out_kernel<<<N_BATCH / 4, 256, 0, stream>>>(Rb, x_val, x_idx, b_aff, out);
    } else {
        direct_kernel<<<N_BATCH, BASE, 0, stream>>>(x_val, W_aff, b_aff, w0, w1,
                                                    x_idx, f0, f1, out);
    }
}